// Round 6
// baseline (12549.777 us; speedup 1.0000x reference)
//
#include <hip/hip_runtime.h>

// Problem constants
#define BB 32      // batch
#define SS 512     // seq len
#define II 512     // input size
#define HH 512     // hidden
#define GG 2048    // 4*H

typedef unsigned short u16;
typedef unsigned int   u32;
typedef unsigned long long u64;

typedef __attribute__((ext_vector_type(8))) short bf16x8;
typedef __attribute__((ext_vector_type(4))) float f32x4;

__device__ __forceinline__ float b2f(u16 h) {
    return __uint_as_float(((u32)h) << 16);
}
__device__ __forceinline__ u16 f2b(float f) {  // RNE f32 -> bf16
    u32 u = __float_as_uint(f);
    u32 r = (u + 0x7FFFu + ((u >> 16) & 1u)) >> 16;
    return (u16)r;
}

// ---- global_load_lds helper (16B per lane, uniform LDS base + lane*16) ----
#ifndef __has_builtin
#define __has_builtin(x) 0
#endif
#if __has_builtin(__builtin_amdgcn_global_load_lds)
#define HAVE_GLL 1
#else
#define HAVE_GLL 0
#endif

typedef __attribute__((address_space(1))) void as1_void;
typedef __attribute__((address_space(3))) void as3_void;

__device__ __forceinline__ void gload16(const void* g, void* l, int lane) {
#if HAVE_GLL
    __builtin_amdgcn_global_load_lds((as1_void*)g, (as3_void*)l, 16, 0, 0);
#else
    *(bf16x8*)((char*)l + lane * 16) = *(const bf16x8*)g;
#endif
}

// ---------------- convert x: [B][S][I] f32 -> [S][B][I] bf16 ----------------
__global__ void k_convert_x(const float* __restrict__ x, u16* __restrict__ xbf) {
    const int n4 = BB * SS * II / 4;  // 2,097,152
    for (int e4 = blockIdx.x * blockDim.x + threadIdx.x; e4 < n4;
         e4 += gridDim.x * blockDim.x) {
        int e = e4 * 4;
        int s = e >> 14;         // / (B*I = 16384)
        int b = (e >> 9) & 31;
        int i = e & 511;
        float4 v = *(const float4*)(x + (size_t)b * (SS * II) + (size_t)s * II + i);
        ushort4 o;
        o.x = f2b(v.x); o.y = f2b(v.y); o.z = f2b(v.z); o.w = f2b(v.w);
        *(ushort4*)(xbf + (size_t)s * (BB * II) + (size_t)b * II + i) = o;
    }
}

// ---------------- generic f32 -> bf16 cast ----------------
__global__ void k_cast(const float* __restrict__ src, u16* __restrict__ dst, int n4) {
    for (int e4 = blockIdx.x * blockDim.x + threadIdx.x; e4 < n4;
         e4 += gridDim.x * blockDim.x) {
        float4 v = *(const float4*)(src + (size_t)e4 * 4);
        ushort4 o;
        o.x = f2b(v.x); o.y = f2b(v.y); o.z = f2b(v.z); o.w = f2b(v.w);
        *(ushort4*)(dst + (size_t)e4 * 4) = o;
    }
}

// ---------------- input projection GEMM (128x128 tile, BK=64, MFMA bf16) ----
#define BKP 64

__launch_bounds__(256)
__global__ void k_proj(const u16* __restrict__ A,
                       const u16* __restrict__ Wf_, const u16* __restrict__ Wb_,
                       const float* __restrict__ bihf, const float* __restrict__ bhhf,
                       const float* __restrict__ bihb, const float* __restrict__ bhhb,
                       u16* __restrict__ xpf, u16* __restrict__ xpb,
                       int K) {
    const int dir = blockIdx.z;
    const u16* Wm = dir ? Wb_ : Wf_;
    const float* bih = dir ? bihb : bihf;
    const float* bhh = dir ? bhhb : bhhf;
    u16* xp = dir ? xpb : xpf;

    __shared__ __align__(16) u16 As[128 * BKP];
    __shared__ __align__(16) u16 Bs[128 * BKP];

    const int t    = threadIdx.x;
    const int lane = t & 63;
    const int w    = t >> 6;
    const int wm   = w >> 1, wn = w & 1;
    const int m0   = blockIdx.x * 128;
    const int n0   = blockIdx.y * 128;

    f32x4 acc[4][4] = {};

    for (int kt = 0; kt < K; kt += BKP) {
        #pragma unroll
        for (int i = 0; i < 4; ++i) {
            int c   = (w * 4 + i) * 64 + lane;   // physical chunk 0..1023
            int row = c >> 3;
            int lc  = (c & 7) ^ (row & 7);       // logical chunk within row
            int gk  = kt + lc * 8;
            gload16(A  + (size_t)(m0 + row) * K + gk, (char*)As + (w * 4 + i) * 1024, lane);
            gload16(Wm + (size_t)(n0 + row) * K + gk, (char*)Bs + (w * 4 + i) * 1024, lane);
        }
        __syncthreads();

        #pragma unroll
        for (int ks = 0; ks < 2; ++ks) {
            const int kc = ks * 4 + (lane >> 4);
            bf16x8 af[4], bfr[4];
            #pragma unroll
            for (int mi = 0; mi < 4; ++mi) {
                int row = wm * 64 + mi * 16 + (lane & 15);
                af[mi] = *(const bf16x8*)&As[row * BKP + ((kc ^ (row & 7)) << 3)];
            }
            #pragma unroll
            for (int ni = 0; ni < 4; ++ni) {
                int row = wn * 64 + ni * 16 + (lane & 15);
                bfr[ni] = *(const bf16x8*)&Bs[row * BKP + ((kc ^ (row & 7)) << 3)];
            }
            #pragma unroll
            for (int mi = 0; mi < 4; ++mi)
                #pragma unroll
                for (int ni = 0; ni < 4; ++ni)
                    acc[mi][ni] = __builtin_amdgcn_mfma_f32_16x16x32_bf16(
                        af[mi], bfr[ni], acc[mi][ni], 0, 0, 0);
        }
        __syncthreads();
    }

    #pragma unroll
    for (int ni = 0; ni < 4; ++ni) {
        int n = n0 + wn * 64 + ni * 16 + (lane & 15);
        float bias = bih[n] + bhh[n];
        #pragma unroll
        for (int mi = 0; mi < 4; ++mi) {
            #pragma unroll
            for (int r = 0; r < 4; ++r) {
                int m = m0 + wm * 64 + mi * 16 + (lane >> 4) * 4 + r;
                xp[(size_t)m * GG + n] = f2b(acc[mi][ni][r] + bias);
            }
        }
    }
}

// ---------------- persistent recurrence kernel (stamped-word exchange) -----
// grid = 32 WGs x 256 thr. dir = bid>>4, wg = bid&15 owns 32 h-cols j0..j0+31
// (128 gate rows). W_hh slice lives in REGISTERS (32 bf16x8 B-fragments per
// thread). h exchanged as epoch-stamped u32 words ((bf16<<16)|stamp) via
// relaxed AGENT-scope atomics (IC-coherent, proven r5). INCREMENTAL poll:
// per-thread pend mask, only stale words are re-loaded (kills the 64KB
// full-reload retries that dominated r5's FETCH_SIZE).
__launch_bounds__(256, 1)
__global__ void k_rec(const u16* __restrict__ xpf, const u16* __restrict__ xpb,
                      const float* __restrict__ whf, const float* __restrict__ whb,
                      u64* __restrict__ Hd,          // [2 par][2 dir][32][256] u64
                      u16* __restrict__ hs0,         // layer0 out [s][b][1024] bf16
                      float* __restrict__ out,       // layer1 out [b][s][1024] f32
                      float* __restrict__ fin,       // final h (65536 f32) then c
                      int layer) {
    const int bid  = blockIdx.x;
    const int dir  = bid >> 4;
    const int wg   = bid & 15;
    const int j0   = wg * 32;
    const u16*  xp = dir ? xpb : xpf;
    const float* W = dir ? whb : whf;

    const int t    = threadIdx.x;
    const int lane = t & 63;
    const int g    = t >> 6;           // wave id = gate

    __shared__ __align__(16) u16 hl[32 * 512];       // h tile, XOR-swizzled (32 KB)
    __shared__ float xq[32 * 129];                   // xp slice f32 (16.5 KB)
    __shared__ float gates[4 * 32 * 33];             // per-gate planes (16.9 KB)

    // ---- W_hh B-fragments -> registers (once). Fragment convention matches
    //      r3/r5's validated Wfr packing: lane (l&15)=gate-row, (l>>4)*8=k-sub.
    bf16x8 Bfr[2][16];
    #pragma unroll
    for (int nb = 0; nb < 2; ++nb) {
        #pragma unroll
        for (int kt = 0; kt < 16; ++kt) {
            const float* src = W + (size_t)(g * 512 + j0 + nb * 16 + (lane & 15)) * 512
                                 + kt * 32 + (lane >> 4) * 8;
            float4 v0 = *(const float4*)src;
            float4 v1 = *(const float4*)(src + 4);
            union { bf16x8 v; u16 a[8]; } u;
            u.a[0] = f2b(v0.x); u.a[1] = f2b(v0.y); u.a[2] = f2b(v0.z); u.a[3] = f2b(v0.w);
            u.a[4] = f2b(v1.x); u.a[5] = f2b(v1.y); u.a[6] = f2b(v1.z); u.a[7] = f2b(v1.w);
            Bfr[nb][kt] = u.v;
        }
    }

    // c-state in registers: thread (b = t>>3, cg = t&7) owns cols j0+cg*4..+3
    float creg[4] = {0.f, 0.f, 0.f, 0.f};
    const int eb = t >> 3;          // epilogue batch row (0..31)
    const int ec = t & 7;           // epilogue col group (0..7)

    // hl stage-write constants: thread t covers bf16 cols (2t, 2t+1) per row
    const int sc_c   = t >> 2;                 // logical 16B chunk within row
    const int sc_sub = (t & 3) * 4;            // byte within chunk

    for (int s = 0; s < SS; ++s) {
        const int sa = dir ? (SS - 1 - s) : s;

        // ---- A: stage xp slice (plain cached loads; overlaps the poll) ----
        {
            int b = t >> 3, seg = t & 7;   // seg>>1 = gate, (seg&1)*16 = half
            const u16* xsrc = xp + (size_t)(sa * 32 + b) * GG
                              + (seg >> 1) * 512 + j0 + (seg & 1) * 16;
            bf16x8 v0 = *(const bf16x8*)xsrc;
            bf16x8 v1 = *(const bf16x8*)(xsrc + 8);
            float* xdst = &xq[b * 129 + (seg >> 1) * 32 + (seg & 1) * 16];
            #pragma unroll
            for (int i = 0; i < 8; ++i) {
                xdst[i]     = b2f((u16)v0[i]);
                xdst[8 + i] = b2f((u16)v1[i]);
            }
        }

        // ---- B: acquire h(s-1): INCREMENTAL stamped poll, then stage ----
        if (s > 0) {
            const u64* Hrd = Hd + ((size_t)((s & 1) * 2 + dir)) * (32 * 256);
            const u32 tgt = (u32)((layer << 10) | s);
            u64 v[32];
            u32 pend = 0xffffffffu;
            for (;;) {
                #pragma unroll
                for (int i = 0; i < 32; ++i) {
                    if (pend & (1u << i)) {
                        u64 w = __hip_atomic_load(Hrd + i * 256 + t, __ATOMIC_RELAXED,
                                                  __HIP_MEMORY_SCOPE_AGENT);
                        if ((((u32)w & 0xffffu) == tgt) &&
                            (((u32)(w >> 32) & 0xffffu) == tgt)) {
                            v[i] = w;
                            pend &= ~(1u << i);
                        }
                    }
                }
                if (__all(pend == 0)) break;
            }
            // stage: row i, bf16 pair (2t, 2t+1) -> 4B LDS write (2-way banks)
            #pragma unroll
            for (int i = 0; i < 32; ++i) {
                u32 two = (u32)((v[i] >> 16) & 0xffffu) | ((u32)(v[i] >> 48) << 16);
                int off = i * 1024 + ((sc_c ^ (i & 7)) << 4) + sc_sub;
                *(u32*)((char*)hl + off) = two;
            }
        } else {
            #pragma unroll
            for (int i = 0; i < 32; ++i) {
                int off = i * 1024 + ((sc_c ^ (i & 7)) << 4) + sc_sub;
                *(u32*)((char*)hl + off) = 0u;
            }
        }
        __syncthreads();   // (1) hl + xq ready

        // ---- C: MFMA, wave g covers gate g over 32 cols, full K=512 ----
        {
            f32x4 acc[2][2];
            #pragma unroll
            for (int mi = 0; mi < 2; ++mi)
                #pragma unroll
                for (int nb = 0; nb < 2; ++nb)
                    acc[mi][nb] = (f32x4){0.f, 0.f, 0.f, 0.f};
            const int b0 = lane & 15, q = lane >> 4;
            #pragma unroll
            for (int kt = 0; kt < 16; ++kt) {
                int pc = ((kt << 2) + q) ^ (b0 & 7);
                bf16x8 a0 = *(const bf16x8*)&hl[b0 * 512 + pc * 8];
                bf16x8 a1 = *(const bf16x8*)&hl[(b0 + 16) * 512 + pc * 8];
                acc[0][0] = __builtin_amdgcn_mfma_f32_16x16x32_bf16(a0, Bfr[0][kt], acc[0][0], 0, 0, 0);
                acc[0][1] = __builtin_amdgcn_mfma_f32_16x16x32_bf16(a0, Bfr[1][kt], acc[0][1], 0, 0, 0);
                acc[1][0] = __builtin_amdgcn_mfma_f32_16x16x32_bf16(a1, Bfr[0][kt], acc[1][0], 0, 0, 0);
                acc[1][1] = __builtin_amdgcn_mfma_f32_16x16x32_bf16(a1, Bfr[1][kt], acc[1][1], 0, 0, 0);
            }
            // plane [g][batch][col32] stride 33: row = mi*16+q*4+r, col = nb*16+b0
            #pragma unroll
            for (int mi = 0; mi < 2; ++mi)
                #pragma unroll
                for (int nb = 0; nb < 2; ++nb)
                    #pragma unroll
                    for (int r = 0; r < 4; ++r)
                        gates[g * 1056 + (mi * 16 + q * 4 + r) * 33 + nb * 16 + b0]
                            = acc[mi][nb][r];
        }
        __syncthreads();   // (2) gates ready

        // ---- D: elementwise epilogue: all 256 threads, (eb, 4 cols) ----
        {
            float hv4[4], cv4[4];
            #pragma unroll
            for (int k = 0; k < 4; ++k) {
                int jj = ec * 4 + k;
                float gi = xq[eb * 129 +      jj] + gates[0 * 1056 + eb * 33 + jj];
                float gf = xq[eb * 129 + 32 + jj] + gates[1 * 1056 + eb * 33 + jj];
                float gg = xq[eb * 129 + 64 + jj] + gates[2 * 1056 + eb * 33 + jj];
                float go = xq[eb * 129 + 96 + jj] + gates[3 * 1056 + eb * 33 + jj];
                float ig = 1.f / (1.f + __expf(-gi));
                float fg = 1.f / (1.f + __expf(-gf));
                float gt = tanhf(gg);
                float og = 1.f / (1.f + __expf(-go));
                float c  = fg * creg[k] + ig * gt;
                float h  = og * tanhf(c);
                creg[k] = c; cv4[k] = c; hv4[k] = h;
            }
            // publish stamped h words (parity ping-pong)
            u64* Hwr = Hd + ((size_t)(((s + 1) & 1) * 2 + dir)) * (32 * 256);
            const u32 pst = (u32)((layer << 10) | (s + 1));
            u32 w0 = ((u32)f2b(hv4[0]) << 16) | pst;
            u32 w1 = ((u32)f2b(hv4[1]) << 16) | pst;
            u32 w2 = ((u32)f2b(hv4[2]) << 16) | pst;
            u32 w3 = ((u32)f2b(hv4[3]) << 16) | pst;
            u64* dst = Hwr + eb * 256 + ((j0 + ec * 4) >> 1);
            __hip_atomic_store(dst,     (u64)w0 | ((u64)w1 << 32),
                               __ATOMIC_RELAXED, __HIP_MEMORY_SCOPE_AGENT);
            __hip_atomic_store(dst + 1, (u64)w2 | ((u64)w3 << 32),
                               __ATOMIC_RELAXED, __HIP_MEMORY_SCOPE_AGENT);

            union { u64 q; u16 a[4]; } ho;
            #pragma unroll
            for (int k = 0; k < 4; ++k) ho.a[k] = f2b(hv4[k]);
            if (layer == 0) {
                *(u64*)(hs0 + (size_t)sa * (BB * 1024) + (size_t)eb * 1024
                        + dir * 512 + j0 + ec * 4) = ho.q;
            } else {
                *(float4*)(out + (size_t)eb * (SS * 1024) + (size_t)sa * 1024
                           + dir * 512 + j0 + ec * 4) =
                    make_float4(hv4[0], hv4[1], hv4[2], hv4[3]);
            }
            if (s == SS - 1) {
                int sl = layer * 2 + dir;
                *(float4*)(fin + (size_t)sl * (32 * 512) + eb * 512 + j0 + ec * 4) =
                    make_float4(hv4[0], hv4[1], hv4[2], hv4[3]);
                *(float4*)(fin + 65536 + (size_t)sl * (32 * 512) + eb * 512 + j0 + ec * 4) =
                    make_float4(cv4[0], cv4[1], cv4[2], cv4[3]);
            }
        }
        __syncthreads();   // (3) xq/gates/hl free for next step
    }
}

// ---------------- workspace layout (bytes) ----------------
#define OFF_XBF   ((size_t)0)                       // 16,777,216
#define OFF_HS0   ((size_t)16777216)                // 33,554,432
#define OFF_XPF   ((size_t)50331648)                // 67,108,864
#define OFF_XPB   ((size_t)117440512)               // 67,108,864
#define OFF_WIH0F ((size_t)184549376)               // 2,097,152
#define OFF_WIH0B ((size_t)186646528)               // 2,097,152
#define OFF_WIH1F ((size_t)188743680)               // 4,194,304
#define OFF_WIH1B ((size_t)192937984)               // 4,194,304
#define OFF_HST   ((size_t)197132288)               // 262,144 (stamped h)

extern "C" void kernel_launch(void* const* d_in, const int* in_sizes, int n_in,
                              void* d_out, int out_size, void* d_ws, size_t ws_size,
                              hipStream_t stream) {
    const float* x      = (const float*)d_in[0];
    const float* wih0f  = (const float*)d_in[1];
    const float* whh0f  = (const float*)d_in[2];
    const float* bih0f  = (const float*)d_in[3];
    const float* bhh0f  = (const float*)d_in[4];
    const float* wih0b  = (const float*)d_in[5];
    const float* whh0b  = (const float*)d_in[6];
    const float* bih0b  = (const float*)d_in[7];
    const float* bhh0b  = (const float*)d_in[8];
    const float* wih1f  = (const float*)d_in[9];
    const float* whh1f  = (const float*)d_in[10];
    const float* bih1f  = (const float*)d_in[11];
    const float* bhh1f  = (const float*)d_in[12];
    const float* wih1b  = (const float*)d_in[13];
    const float* whh1b  = (const float*)d_in[14];
    const float* bih1b  = (const float*)d_in[15];
    const float* bhh1b  = (const float*)d_in[16];

    float* out = (float*)d_out;
    char* ws = (char*)d_ws;

    u16* xbf    = (u16*)(ws + OFF_XBF);
    u16* hs0    = (u16*)(ws + OFF_HS0);
    u16* xpf    = (u16*)(ws + OFF_XPF);
    u16* xpb    = (u16*)(ws + OFF_XPB);
    u16* bwih0f = (u16*)(ws + OFF_WIH0F);
    u16* bwih0b = (u16*)(ws + OFF_WIH0B);
    u16* bwih1f = (u16*)(ws + OFF_WIH1F);
    u16* bwih1b = (u16*)(ws + OFF_WIH1B);
    u64* Hd     = (u64*)(ws + OFF_HST);
    float* fin  = out + 16777216;   // final h stack, then c stack at +65536

    // converts
    k_convert_x<<<1024, 256, 0, stream>>>(x, xbf);
    k_cast<<<512, 256, 0, stream>>>(wih0f, bwih0f, 2048 * 512 / 4);
    k_cast<<<512, 256, 0, stream>>>(wih0b, bwih0b, 2048 * 512 / 4);
    k_cast<<<512, 256, 0, stream>>>(wih1f, bwih1f, 2048 * 1024 / 4);
    k_cast<<<512, 256, 0, stream>>>(wih1b, bwih1b, 2048 * 1024 / 4);

    // zero stamped-h buffer once (first-call garbage; stale stamps are
    // layer-tagged so no inter-layer or inter-replay reset is needed)
    hipMemsetAsync(ws + OFF_HST, 0, 262144, stream);

    // layer 0
    k_proj<<<dim3(128, 16, 2), 256, 0, stream>>>(
        xbf, bwih0f, bwih0b, bih0f, bhh0f, bih0b, bhh0b, xpf, xpb, 512);
    k_rec<<<32, 256, 0, stream>>>(xpf, xpb, whh0f, whh0b, Hd,
                                  hs0, nullptr, fin, 0);

    // layer 1
    k_proj<<<dim3(128, 16, 2), 256, 0, stream>>>(
        hs0, bwih1f, bwih1b, bih1f, bhh1f, bih1b, bhh1b, xpf, xpb, 1024);
    k_rec<<<32, 256, 0, stream>>>(xpf, xpb, whh1f, whh1b, Hd,
                                  nullptr, out, fin, 1);
}

// Round 7
// 7922.993 us; speedup vs baseline: 1.5840x; 1.5840x over previous
//
#include <hip/hip_runtime.h>

// Problem constants
#define BB 32      // batch
#define SS 512     // seq len
#define II 512     // input size
#define HH 512     // hidden
#define GG 2048    // 4*H

typedef unsigned short u16;
typedef unsigned int   u32;
typedef unsigned long long u64;

typedef __attribute__((ext_vector_type(8))) short bf16x8;
typedef __attribute__((ext_vector_type(4))) float f32x4;

__device__ __forceinline__ float b2f(u16 h) {
    return __uint_as_float(((u32)h) << 16);
}
__device__ __forceinline__ u16 f2b(float f) {  // RNE f32 -> bf16
    u32 u = __float_as_uint(f);
    u32 r = (u + 0x7FFFu + ((u >> 16) & 1u)) >> 16;
    return (u16)r;
}

// ---- global_load_lds helper (16B per lane, uniform LDS base + lane*16) ----
#ifndef __has_builtin
#define __has_builtin(x) 0
#endif
#if __has_builtin(__builtin_amdgcn_global_load_lds)
#define HAVE_GLL 1
#else
#define HAVE_GLL 0
#endif

typedef __attribute__((address_space(1))) void as1_void;
typedef __attribute__((address_space(3))) void as3_void;

__device__ __forceinline__ void gload16(const void* g, void* l, int lane) {
#if HAVE_GLL
    __builtin_amdgcn_global_load_lds((as1_void*)g, (as3_void*)l, 16, 0, 0);
#else
    *(bf16x8*)((char*)l + lane * 16) = *(const bf16x8*)g;
#endif
}

// ---------------- convert x: [B][S][I] f32 -> [S][B][I] bf16 ----------------
__global__ void k_convert_x(const float* __restrict__ x, u16* __restrict__ xbf) {
    const int n4 = BB * SS * II / 4;  // 2,097,152
    for (int e4 = blockIdx.x * blockDim.x + threadIdx.x; e4 < n4;
         e4 += gridDim.x * blockDim.x) {
        int e = e4 * 4;
        int s = e >> 14;         // / (B*I = 16384)
        int b = (e >> 9) & 31;
        int i = e & 511;
        float4 v = *(const float4*)(x + (size_t)b * (SS * II) + (size_t)s * II + i);
        ushort4 o;
        o.x = f2b(v.x); o.y = f2b(v.y); o.z = f2b(v.z); o.w = f2b(v.w);
        *(ushort4*)(xbf + (size_t)s * (BB * II) + (size_t)b * II + i) = o;
    }
}

// ---------------- generic f32 -> bf16 cast ----------------
__global__ void k_cast(const float* __restrict__ src, u16* __restrict__ dst, int n4) {
    for (int e4 = blockIdx.x * blockDim.x + threadIdx.x; e4 < n4;
         e4 += gridDim.x * blockDim.x) {
        float4 v = *(const float4*)(src + (size_t)e4 * 4);
        ushort4 o;
        o.x = f2b(v.x); o.y = f2b(v.y); o.z = f2b(v.z); o.w = f2b(v.w);
        *(ushort4*)(dst + (size_t)e4 * 4) = o;
    }
}

// ---------------- input projection GEMM (128x128 tile, BK=64, MFMA bf16) ----
#define BKP 64

__launch_bounds__(256)
__global__ void k_proj(const u16* __restrict__ A,
                       const u16* __restrict__ Wf_, const u16* __restrict__ Wb_,
                       const float* __restrict__ bihf, const float* __restrict__ bhhf,
                       const float* __restrict__ bihb, const float* __restrict__ bhhb,
                       u16* __restrict__ xpf, u16* __restrict__ xpb,
                       int K) {
    const int dir = blockIdx.z;
    const u16* Wm = dir ? Wb_ : Wf_;
    const float* bih = dir ? bihb : bihf;
    const float* bhh = dir ? bhhb : bhhf;
    u16* xp = dir ? xpb : xpf;

    __shared__ __align__(16) u16 As[128 * BKP];
    __shared__ __align__(16) u16 Bs[128 * BKP];

    const int t    = threadIdx.x;
    const int lane = t & 63;
    const int w    = t >> 6;
    const int wm   = w >> 1, wn = w & 1;
    const int m0   = blockIdx.x * 128;
    const int n0   = blockIdx.y * 128;

    f32x4 acc[4][4] = {};

    for (int kt = 0; kt < K; kt += BKP) {
        #pragma unroll
        for (int i = 0; i < 4; ++i) {
            int c   = (w * 4 + i) * 64 + lane;   // physical chunk 0..1023
            int row = c >> 3;
            int lc  = (c & 7) ^ (row & 7);       // logical chunk within row
            int gk  = kt + lc * 8;
            gload16(A  + (size_t)(m0 + row) * K + gk, (char*)As + (w * 4 + i) * 1024, lane);
            gload16(Wm + (size_t)(n0 + row) * K + gk, (char*)Bs + (w * 4 + i) * 1024, lane);
        }
        __syncthreads();

        #pragma unroll
        for (int ks = 0; ks < 2; ++ks) {
            const int kc = ks * 4 + (lane >> 4);
            bf16x8 af[4], bfr[4];
            #pragma unroll
            for (int mi = 0; mi < 4; ++mi) {
                int row = wm * 64 + mi * 16 + (lane & 15);
                af[mi] = *(const bf16x8*)&As[row * BKP + ((kc ^ (row & 7)) << 3)];
            }
            #pragma unroll
            for (int ni = 0; ni < 4; ++ni) {
                int row = wn * 64 + ni * 16 + (lane & 15);
                bfr[ni] = *(const bf16x8*)&Bs[row * BKP + ((kc ^ (row & 7)) << 3)];
            }
            #pragma unroll
            for (int mi = 0; mi < 4; ++mi)
                #pragma unroll
                for (int ni = 0; ni < 4; ++ni)
                    acc[mi][ni] = __builtin_amdgcn_mfma_f32_16x16x32_bf16(
                        af[mi], bfr[ni], acc[mi][ni], 0, 0, 0);
        }
        __syncthreads();
    }

    #pragma unroll
    for (int ni = 0; ni < 4; ++ni) {
        int n = n0 + wn * 64 + ni * 16 + (lane & 15);
        float bias = bih[n] + bhh[n];
        #pragma unroll
        for (int mi = 0; mi < 4; ++mi) {
            #pragma unroll
            for (int r = 0; r < 4; ++r) {
                int m = m0 + wm * 64 + mi * 16 + (lane >> 4) * 4 + r;
                xp[(size_t)m * GG + n] = f2b(acc[mi][ni][r] + bias);
            }
        }
    }
}

// ---------------- persistent recurrence kernel (stamped-word exchange) -----
// grid = 64 WGs x 256 thr. dir = bid>>5, wg = bid&31 owns 16 h-cols j0..j0+15.
// h exchanged as epoch-stamped u32 words ((bf16<<16)|stamp) via relaxed
// AGENT-scope atomics (IC-coherent, proven r5). Round-7 changes:
//  - per-THREAD poll exit (each thread's 32 words come from ONE producer WG)
//  - per-kt LDS ready flags (monotonic counters): MFMA consumes k-tiles as
//    they arrive; wave g starts at its own staged tiles (kt = (4g+kk)&15)
//  - no whole-WG barrier between poll and MFMA
__launch_bounds__(256)
__global__ void k_rec(const u16* __restrict__ xpf, const u16* __restrict__ xpb,
                      const float* __restrict__ whf, const float* __restrict__ whb,
                      u64* __restrict__ Hd,          // [2 par][2 dir][32][256] u64
                      u16* __restrict__ hs0,         // layer0 out [s][b][1024] bf16
                      float* __restrict__ out,       // layer1 out [b][s][1024] f32
                      float* __restrict__ fin,       // final h (65536 f32) then c
                      int layer) {
    const int bid  = blockIdx.x;
    const int dir  = bid >> 5;
    const int wg   = bid & 31;
    const int j0   = wg * 16;
    const u16*  xp = dir ? xpb : xpf;
    const float* W = dir ? whb : whf;

    const int t    = threadIdx.x;
    const int lane = t & 63;
    const int g    = t >> 6;           // wave id = gate

    __shared__ __align__(16) u16 Wfr[64 * 64 * 8];   // frag-order W slice (64 KB)
    __shared__ __align__(16) u16 hl[32 * 512];       // h tile, XOR-swizzled (32 KB)
    __shared__ float xq[32 * 65];                    // xp slice f32
    __shared__ float gates[4 * 32 * 18];             // per-gate planes, stride 18
    __shared__ u32 ktdone[16];                       // monotonic k-tile counters

    // ---- pack W_hh slice into fragment order (once; validated r3/r5) ----
    for (int it = 0; it < 16; ++it) {
        int task = it * 256 + t;           // 0..4095
        int l    = task & 63;
        int blk  = task >> 6;              // 0..63 = gate*16 + ktile
        int gg   = blk >> 4;
        int kt   = blk & 15;
        const float* src = W + (size_t)(gg * 512 + j0 + (l & 15)) * 512
                             + kt * 32 + (l >> 4) * 8;
        float4 v0 = *(const float4*)src;
        float4 v1 = *(const float4*)(src + 4);
        union { bf16x8 v; u16 a[8]; } u;
        u.a[0] = f2b(v0.x); u.a[1] = f2b(v0.y); u.a[2] = f2b(v0.z); u.a[3] = f2b(v0.w);
        u.a[4] = f2b(v1.x); u.a[5] = f2b(v1.y); u.a[6] = f2b(v1.z); u.a[7] = f2b(v1.w);
        *(bf16x8*)&Wfr[task * 8] = u.v;
    }
    if (t < 16) ktdone[t] = 0u;
    __syncthreads();

    // c-state in registers of epilogue threads (t<128): 4 cols each
    float creg[4] = {0.f, 0.f, 0.f, 0.f};
    const int eb = t >> 2;          // epilogue batch row (0..31)
    const int ej = t & 3;           // epilogue col group -> cols j0+ej*4..+3

    // stage-write constants: thread t covers word t = bf16 cols (2t, 2t+1)
    const int sc_c   = t >> 2;                 // logical 16B chunk within row
    const int sc_sub = (t & 3) * 4;            // byte within chunk

    for (int s = 0; s < SS; ++s) {
        const int sa = dir ? (SS - 1 - s) : s;

        // ---- A: issue poll pass-1 loads FIRST (critical path) ----
        u64 w[32];
        const u64* Hrd = Hd + ((size_t)((s & 1) * 2 + dir)) * (32 * 256);
        const u32 tgt = (u32)((layer << 10) | s);
        if (s > 0) {
            #pragma unroll
            for (int i = 0; i < 32; ++i)
                w[i] = __hip_atomic_load(Hrd + i * 256 + t, __ATOMIC_RELAXED,
                                         __HIP_MEMORY_SCOPE_AGENT);
        }

        // ---- B: stage xp slice (issue + convert hides poll latency) ----
        if (t < 128) {
            int b = t & 31, gq = t >> 5;
            const u16* xsrc = xp + (size_t)(sa * 32 + b) * GG + gq * 512 + j0;
            bf16x8 v0 = *(const bf16x8*)xsrc;
            bf16x8 v1 = *(const bf16x8*)(xsrc + 8);
            #pragma unroll
            for (int i = 0; i < 8; ++i) {
                xq[b * 65 + gq * 16 + i]     = b2f((u16)v0[i]);
                xq[b * 65 + gq * 16 + 8 + i] = b2f((u16)v1[i]);
            }
        }

        // ---- C: per-thread check + batched retry, then stage to LDS ----
        if (s > 0) {
            for (;;) {
                bool ok = true;
                #pragma unroll
                for (int i = 0; i < 32; ++i) {
                    ok = ok && (((u32)w[i] & 0xffffu) == tgt)
                            && ((((u32)(w[i] >> 32)) & 0xffffu) == tgt);
                }
                if (ok) break;
                #pragma unroll
                for (int i = 0; i < 32; ++i)
                    w[i] = __hip_atomic_load(Hrd + i * 256 + t, __ATOMIC_RELAXED,
                                             __HIP_MEMORY_SCOPE_AGENT);
            }
            #pragma unroll
            for (int i = 0; i < 32; ++i) {
                u32 two = (u32)((w[i] >> 16) & 0xffffu) | ((u32)(w[i] >> 48) << 16);
                int off = i * 1024 + ((sc_c ^ (i & 7)) << 4) + sc_sub;
                *(u32*)((char*)hl + off) = two;
            }
        } else {
            #pragma unroll
            for (int i = 0; i < 32; ++i) {
                int off = i * 1024 + ((sc_c ^ (i & 7)) << 4) + sc_sub;
                *(u32*)((char*)hl + off) = 0u;
            }
        }
        // hl writes retired before flagging this thread's k-tile
        asm volatile("s_waitcnt lgkmcnt(0)" ::: "memory");
        atomicAdd(&ktdone[t >> 4], 1u);

        // ---- D: MFMA, wave g = gate g; consume k-tiles as they arrive,
        //         starting with the tiles this wave itself staged ----
        {
            f32x4 acc0 = {0.f, 0.f, 0.f, 0.f}, acc1 = {0.f, 0.f, 0.f, 0.f};
            const int b0 = lane & 15, q = lane >> 4;
            const u32 kneed = 16u * (u32)(s + 1);
            #pragma unroll
            for (int kk = 0; kk < 16; ++kk) {
                const int kt = (g * 4 + kk) & 15;
                while (__hip_atomic_load(&ktdone[kt], __ATOMIC_RELAXED,
                                         __HIP_MEMORY_SCOPE_WORKGROUP) < kneed) {
                    __builtin_amdgcn_s_sleep(1);
                }
                asm volatile("" ::: "memory");          // block IR-level hoisting
                __builtin_amdgcn_sched_barrier(0);      // block MIR scheduler (rule #18)
                int pc = ((kt << 2) + q) ^ (b0 & 7);
                bf16x8 a0 = *(const bf16x8*)&hl[b0 * 512 + pc * 8];
                bf16x8 a1 = *(const bf16x8*)&hl[(b0 + 16) * 512 + pc * 8];
                bf16x8 Bv = *(const bf16x8*)&Wfr[((g * 16 + kt) * 64 + lane) * 8];
                acc0 = __builtin_amdgcn_mfma_f32_16x16x32_bf16(a0, Bv, acc0, 0, 0, 0);
                acc1 = __builtin_amdgcn_mfma_f32_16x16x32_bf16(a1, Bv, acc1, 0, 0, 0);
            }
            // plane [g][batch][jj], batch-stride 18: row = q*4+r (+16), col = b0
            #pragma unroll
            for (int r = 0; r < 4; ++r) {
                gates[g * 576 + (q * 4 + r) * 18 + b0]      = acc0[r];
                gates[g * 576 + (16 + q * 4 + r) * 18 + b0] = acc1[r];
            }
        }
        __syncthreads();   // (1) gates + xq ready for epilogue

        // ---- E: elementwise epilogue (t<128): (eb, cols j0+ej*4..+3) ----
        if (t < 128) {
            float hv4[4], cv4[4];
            #pragma unroll
            for (int k = 0; k < 4; ++k) {
                int jj = ej * 4 + k;
                float gi = xq[eb * 65 +      jj] + gates[0 * 576 + eb * 18 + jj];
                float gf = xq[eb * 65 + 16 + jj] + gates[1 * 576 + eb * 18 + jj];
                float gg = xq[eb * 65 + 32 + jj] + gates[2 * 576 + eb * 18 + jj];
                float go = xq[eb * 65 + 48 + jj] + gates[3 * 576 + eb * 18 + jj];
                float ig = 1.f / (1.f + __expf(-gi));
                float fg = 1.f / (1.f + __expf(-gf));
                float gt = tanhf(gg);
                float og = 1.f / (1.f + __expf(-go));
                float c  = fg * creg[k] + ig * gt;
                float h  = og * tanhf(c);
                creg[k] = c; cv4[k] = c; hv4[k] = h;
            }
            // publish stamped h words FIRST (critical path), parity ping-pong
            u64* Hwr = Hd + ((size_t)(((s + 1) & 1) * 2 + dir)) * (32 * 256);
            const u32 pst = (u32)((layer << 10) | (s + 1));
            u32 w0 = ((u32)f2b(hv4[0]) << 16) | pst;
            u32 w1 = ((u32)f2b(hv4[1]) << 16) | pst;
            u32 w2 = ((u32)f2b(hv4[2]) << 16) | pst;
            u32 w3 = ((u32)f2b(hv4[3]) << 16) | pst;
            u64* dst = Hwr + eb * 256 + ((j0 + ej * 4) >> 1);
            __hip_atomic_store(dst,     (u64)w0 | ((u64)w1 << 32),
                               __ATOMIC_RELAXED, __HIP_MEMORY_SCOPE_AGENT);
            __hip_atomic_store(dst + 1, (u64)w2 | ((u64)w3 << 32),
                               __ATOMIC_RELAXED, __HIP_MEMORY_SCOPE_AGENT);

            union { u64 q; u16 a[4]; } ho;
            #pragma unroll
            for (int k = 0; k < 4; ++k) ho.a[k] = f2b(hv4[k]);
            if (layer == 0) {
                *(u64*)(hs0 + (size_t)sa * (BB * 1024) + (size_t)eb * 1024
                        + dir * 512 + j0 + ej * 4) = ho.q;
            } else {
                *(float4*)(out + (size_t)eb * (SS * 1024) + (size_t)sa * 1024
                           + dir * 512 + j0 + ej * 4) =
                    make_float4(hv4[0], hv4[1], hv4[2], hv4[3]);
            }
            if (s == SS - 1) {
                int sl = layer * 2 + dir;
                *(float4*)(fin + (size_t)sl * (32 * 512) + eb * 512 + j0 + ej * 4) =
                    make_float4(hv4[0], hv4[1], hv4[2], hv4[3]);
                *(float4*)(fin + 65536 + (size_t)sl * (32 * 512) + eb * 512 + j0 + ej * 4) =
                    make_float4(cv4[0], cv4[1], cv4[2], cv4[3]);
            }
        }
        __syncthreads();   // (2) xq/gates/hl free for next step
    }
}

// ---------------- workspace layout (bytes) ----------------
#define OFF_XBF   ((size_t)0)                       // 16,777,216
#define OFF_HS0   ((size_t)16777216)                // 33,554,432
#define OFF_XPF   ((size_t)50331648)                // 67,108,864
#define OFF_XPB   ((size_t)117440512)               // 67,108,864
#define OFF_WIH0F ((size_t)184549376)               // 2,097,152
#define OFF_WIH0B ((size_t)186646528)               // 2,097,152
#define OFF_WIH1F ((size_t)188743680)               // 4,194,304
#define OFF_WIH1B ((size_t)192937984)               // 4,194,304
#define OFF_HST   ((size_t)197132288)               // 262,144 (stamped h)

extern "C" void kernel_launch(void* const* d_in, const int* in_sizes, int n_in,
                              void* d_out, int out_size, void* d_ws, size_t ws_size,
                              hipStream_t stream) {
    const float* x      = (const float*)d_in[0];
    const float* wih0f  = (const float*)d_in[1];
    const float* whh0f  = (const float*)d_in[2];
    const float* bih0f  = (const float*)d_in[3];
    const float* bhh0f  = (const float*)d_in[4];
    const float* wih0b  = (const float*)d_in[5];
    const float* whh0b  = (const float*)d_in[6];
    const float* bih0b  = (const float*)d_in[7];
    const float* bhh0b  = (const float*)d_in[8];
    const float* wih1f  = (const float*)d_in[9];
    const float* whh1f  = (const float*)d_in[10];
    const float* bih1f  = (const float*)d_in[11];
    const float* bhh1f  = (const float*)d_in[12];
    const float* wih1b  = (const float*)d_in[13];
    const float* whh1b  = (const float*)d_in[14];
    const float* bih1b  = (const float*)d_in[15];
    const float* bhh1b  = (const float*)d_in[16];

    float* out = (float*)d_out;
    char* ws = (char*)d_ws;

    u16* xbf    = (u16*)(ws + OFF_XBF);
    u16* hs0    = (u16*)(ws + OFF_HS0);
    u16* xpf    = (u16*)(ws + OFF_XPF);
    u16* xpb    = (u16*)(ws + OFF_XPB);
    u16* bwih0f = (u16*)(ws + OFF_WIH0F);
    u16* bwih0b = (u16*)(ws + OFF_WIH0B);
    u16* bwih1f = (u16*)(ws + OFF_WIH1F);
    u16* bwih1b = (u16*)(ws + OFF_WIH1B);
    u64* Hd     = (u64*)(ws + OFF_HST);
    float* fin  = out + 16777216;   // final h stack, then c stack at +65536

    // converts
    k_convert_x<<<1024, 256, 0, stream>>>(x, xbf);
    k_cast<<<512, 256, 0, stream>>>(wih0f, bwih0f, 2048 * 512 / 4);
    k_cast<<<512, 256, 0, stream>>>(wih0b, bwih0b, 2048 * 512 / 4);
    k_cast<<<512, 256, 0, stream>>>(wih1f, bwih1f, 2048 * 1024 / 4);
    k_cast<<<512, 256, 0, stream>>>(wih1b, bwih1b, 2048 * 1024 / 4);

    // zero stamped-h buffer once (first-call garbage; stale stamps are
    // layer-tagged so no inter-layer or inter-replay reset is needed)
    hipMemsetAsync(ws + OFF_HST, 0, 262144, stream);

    // layer 0
    k_proj<<<dim3(128, 16, 2), 256, 0, stream>>>(
        xbf, bwih0f, bwih0b, bih0f, bhh0f, bih0b, bhh0b, xpf, xpb, 512);
    k_rec<<<64, 256, 0, stream>>>(xpf, xpb, whh0f, whh0b, Hd,
                                  hs0, nullptr, fin, 0);

    // layer 1
    k_proj<<<dim3(128, 16, 2), 256, 0, stream>>>(
        hs0, bwih1f, bwih1b, bih1f, bhh1f, bih1b, bhh1b, xpf, xpb, 1024);
    k_rec<<<64, 256, 0, stream>>>(xpf, xpb, whh1f, whh1b, Hd,
                                  nullptr, out, fin, 1);
}

// Round 8
// 5740.668 us; speedup vs baseline: 2.1861x; 1.3802x over previous
//
#include <hip/hip_runtime.h>

// Problem constants
#define BB 32      // batch
#define SS 512     // seq len
#define II 512     // input size
#define HH 512     // hidden
#define GG 2048    // 4*H

typedef unsigned short u16;
typedef unsigned int   u32;
typedef unsigned long long u64;

typedef __attribute__((ext_vector_type(8))) short bf16x8;
typedef __attribute__((ext_vector_type(4))) float f32x4;

__device__ __forceinline__ float b2f(u16 h) {
    return __uint_as_float(((u32)h) << 16);
}
__device__ __forceinline__ u16 f2b(float f) {  // RNE f32 -> bf16
    u32 u = __float_as_uint(f);
    u32 r = (u + 0x7FFFu + ((u >> 16) & 1u)) >> 16;
    return (u16)r;
}

// ---- global_load_lds helper (16B per lane, uniform LDS base + lane*16) ----
#ifndef __has_builtin
#define __has_builtin(x) 0
#endif
#if __has_builtin(__builtin_amdgcn_global_load_lds)
#define HAVE_GLL 1
#else
#define HAVE_GLL 0
#endif

typedef __attribute__((address_space(1))) void as1_void;
typedef __attribute__((address_space(3))) void as3_void;

__device__ __forceinline__ void gload16(const void* g, void* l, int lane) {
#if HAVE_GLL
    __builtin_amdgcn_global_load_lds((as1_void*)g, (as3_void*)l, 16, 0, 0);
#else
    *(bf16x8*)((char*)l + lane * 16) = *(const bf16x8*)g;
#endif
}

// ---------------- convert x: [B][S][I] f32 -> [S][B][I] bf16 ----------------
__global__ void k_convert_x(const float* __restrict__ x, u16* __restrict__ xbf) {
    const int n4 = BB * SS * II / 4;  // 2,097,152
    for (int e4 = blockIdx.x * blockDim.x + threadIdx.x; e4 < n4;
         e4 += gridDim.x * blockDim.x) {
        int e = e4 * 4;
        int s = e >> 14;         // / (B*I = 16384)
        int b = (e >> 9) & 31;
        int i = e & 511;
        float4 v = *(const float4*)(x + (size_t)b * (SS * II) + (size_t)s * II + i);
        ushort4 o;
        o.x = f2b(v.x); o.y = f2b(v.y); o.z = f2b(v.z); o.w = f2b(v.w);
        *(ushort4*)(xbf + (size_t)s * (BB * II) + (size_t)b * II + i) = o;
    }
}

// ---------------- generic f32 -> bf16 cast ----------------
__global__ void k_cast(const float* __restrict__ src, u16* __restrict__ dst, int n4) {
    for (int e4 = blockIdx.x * blockDim.x + threadIdx.x; e4 < n4;
         e4 += gridDim.x * blockDim.x) {
        float4 v = *(const float4*)(src + (size_t)e4 * 4);
        ushort4 o;
        o.x = f2b(v.x); o.y = f2b(v.y); o.z = f2b(v.z); o.w = f2b(v.w);
        *(ushort4*)(dst + (size_t)e4 * 4) = o;
    }
}

// ---------------- input projection GEMM (128x128 tile, BK=64, MFMA bf16) ----
#define BKP 64

__launch_bounds__(256)
__global__ void k_proj(const u16* __restrict__ A,
                       const u16* __restrict__ Wf_, const u16* __restrict__ Wb_,
                       const float* __restrict__ bihf, const float* __restrict__ bhhf,
                       const float* __restrict__ bihb, const float* __restrict__ bhhb,
                       u16* __restrict__ xpf, u16* __restrict__ xpb,
                       int K) {
    const int dir = blockIdx.z;
    const u16* Wm = dir ? Wb_ : Wf_;
    const float* bih = dir ? bihb : bihf;
    const float* bhh = dir ? bhhb : bhhf;
    u16* xp = dir ? xpb : xpf;

    __shared__ __align__(16) u16 As[128 * BKP];
    __shared__ __align__(16) u16 Bs[128 * BKP];

    const int t    = threadIdx.x;
    const int lane = t & 63;
    const int w    = t >> 6;
    const int wm   = w >> 1, wn = w & 1;
    const int m0   = blockIdx.x * 128;
    const int n0   = blockIdx.y * 128;

    f32x4 acc[4][4] = {};

    for (int kt = 0; kt < K; kt += BKP) {
        #pragma unroll
        for (int i = 0; i < 4; ++i) {
            int c   = (w * 4 + i) * 64 + lane;   // physical chunk 0..1023
            int row = c >> 3;
            int lc  = (c & 7) ^ (row & 7);       // logical chunk within row
            int gk  = kt + lc * 8;
            gload16(A  + (size_t)(m0 + row) * K + gk, (char*)As + (w * 4 + i) * 1024, lane);
            gload16(Wm + (size_t)(n0 + row) * K + gk, (char*)Bs + (w * 4 + i) * 1024, lane);
        }
        __syncthreads();

        #pragma unroll
        for (int ks = 0; ks < 2; ++ks) {
            const int kc = ks * 4 + (lane >> 4);
            bf16x8 af[4], bfr[4];
            #pragma unroll
            for (int mi = 0; mi < 4; ++mi) {
                int row = wm * 64 + mi * 16 + (lane & 15);
                af[mi] = *(const bf16x8*)&As[row * BKP + ((kc ^ (row & 7)) << 3)];
            }
            #pragma unroll
            for (int ni = 0; ni < 4; ++ni) {
                int row = wn * 64 + ni * 16 + (lane & 15);
                bfr[ni] = *(const bf16x8*)&Bs[row * BKP + ((kc ^ (row & 7)) << 3)];
            }
            #pragma unroll
            for (int mi = 0; mi < 4; ++mi)
                #pragma unroll
                for (int ni = 0; ni < 4; ++ni)
                    acc[mi][ni] = __builtin_amdgcn_mfma_f32_16x16x32_bf16(
                        af[mi], bfr[ni], acc[mi][ni], 0, 0, 0);
        }
        __syncthreads();
    }

    #pragma unroll
    for (int ni = 0; ni < 4; ++ni) {
        int n = n0 + wn * 64 + ni * 16 + (lane & 15);
        float bias = bih[n] + bhh[n];
        #pragma unroll
        for (int mi = 0; mi < 4; ++mi) {
            #pragma unroll
            for (int r = 0; r < 4; ++r) {
                int m = m0 + wm * 64 + mi * 16 + (lane >> 4) * 4 + r;
                xp[(size_t)m * GG + n] = f2b(acc[mi][ni][r] + bias);
            }
        }
    }
}

// ---------------- persistent recurrence kernel (stamped-word exchange) -----
// grid = 64 WGs x 512 thr (8 waves). dir = bid>>5, wg = bid&31 owns 16 h-cols.
// Wave w: gate g = w&3, batch-half m = w>>2 -> 16 MFMA/step/wave.
// h exchanged as epoch-stamped u32 words ((bf16<<16)|stamp) via relaxed
// AGENT-scope atomics (IC-coherent, proven r5). Poll is software-pipelined:
// next step's 16 loads are ISSUED in the epilogue right after publish (no
// barrier in between), checked at loop top; full batched reload on retry.
// 2 barriers/step (stage->MFMA, MFMA->epilogue); xq double-buffered so the
// 3rd barrier is unnecessary (uniform barrier counts -> no phase slip).
__launch_bounds__(512, 1)
__global__ void k_rec(const u16* __restrict__ xpf, const u16* __restrict__ xpb,
                      const float* __restrict__ whf, const float* __restrict__ whb,
                      u64* __restrict__ Hd,          // [2 par][2 dir][32][256] u64
                      u16* __restrict__ hs0,         // layer0 out [s][b][1024] bf16
                      float* __restrict__ out,       // layer1 out [b][s][1024] f32
                      float* __restrict__ fin,       // final h (65536 f32) then c
                      int layer) {
    const int bid  = blockIdx.x;
    const int dir  = bid >> 5;
    const int wg   = bid & 31;
    const int j0   = wg * 16;
    const u16*  xp = dir ? xpb : xpf;
    const float* W = dir ? whb : whf;

    const int t    = threadIdx.x;
    const int lane = t & 63;
    const int wv   = t >> 6;           // wave 0..7
    const int g    = wv & 3;           // gate
    const int m    = wv >> 2;          // batch half

    __shared__ __align__(16) u16 Wfr[64 * 64 * 8];   // frag-order W slice (64 KB)
    __shared__ __align__(16) u16 hl[32 * 512];       // h tile, XOR-swizzled (32 KB)
    __shared__ float xq[2][32 * 65];                 // xp slice f32, DOUBLE-BUFFERED
    __shared__ float gates[4 * 32 * 18];             // per-gate planes, stride 18

    // ---- pack W_hh slice into fragment order (once; validated r3/r5) ----
    for (int it = 0; it < 8; ++it) {
        int task = it * 512 + t;           // 0..4095
        int l    = task & 63;
        int blk  = task >> 6;              // 0..63 = gate*16 + ktile
        int gg   = blk >> 4;
        int kt   = blk & 15;
        const float* src = W + (size_t)(gg * 512 + j0 + (l & 15)) * 512
                             + kt * 32 + (l >> 4) * 8;
        float4 v0 = *(const float4*)src;
        float4 v1 = *(const float4*)(src + 4);
        union { bf16x8 v; u16 a[8]; } u;
        u.a[0] = f2b(v0.x); u.a[1] = f2b(v0.y); u.a[2] = f2b(v0.z); u.a[3] = f2b(v0.w);
        u.a[4] = f2b(v1.x); u.a[5] = f2b(v1.y); u.a[6] = f2b(v1.z); u.a[7] = f2b(v1.w);
        *(bf16x8*)&Wfr[task * 8] = u.v;
    }
    __syncthreads();

    // poll/stage mapping: thread t covers rows r0..r0+15, word wd (cols 2wd,2wd+1)
    const int wd   = t & 255;
    const int r0   = (t >> 8) * 16;
    const int sc_c   = wd >> 2;            // logical 16B chunk within row
    const int sc_sub = (wd & 3) * 4;       // byte within chunk

    // epilogue mapping: thread t -> (batch eb, col ej), ONE column per thread
    const int eb = t >> 4;                 // 0..31
    const int ej = t & 15;                 // 0..15
    float creg = 0.f;

    u64 w[16];                             // software-pipelined poll registers

    for (int s = 0; s < SS; ++s) {
        const int sa = dir ? (SS - 1 - s) : s;

        // ---- A: stage xp slice into xq[s&1] (global loads overlap poll) ----
        if (t < 256) {
            int b = t & 31, seg = t >> 5;          // seg: gate*2 + half
            int gq = seg >> 1, hf = seg & 1;
            const u16* xsrc = xp + (size_t)(sa * 32 + b) * GG + gq * 512 + j0 + hf * 8;
            bf16x8 v0 = *(const bf16x8*)xsrc;
            float* xdst = &xq[s & 1][b * 65 + gq * 16 + hf * 8];
            #pragma unroll
            for (int i = 0; i < 8; ++i) xdst[i] = b2f((u16)v0[i]);
        }

        // ---- B: check prefetched stamped words; batched full retry ----
        if (s > 0) {
            const u64* Hrd = Hd + ((size_t)((s & 1) * 2 + dir)) * (32 * 256);
            const u32 tgt = (u32)((layer << 10) | s);
            for (;;) {
                bool ok = true;
                #pragma unroll
                for (int i = 0; i < 16; ++i) {
                    ok = ok && (((u32)w[i] & 0xffffu) == tgt)
                            && ((((u32)(w[i] >> 32)) & 0xffffu) == tgt);
                }
                if (ok) break;
                #pragma unroll
                for (int i = 0; i < 16; ++i)
                    w[i] = __hip_atomic_load(Hrd + (r0 + i) * 256 + wd,
                                             __ATOMIC_RELAXED, __HIP_MEMORY_SCOPE_AGENT);
            }
            #pragma unroll
            for (int i = 0; i < 16; ++i) {
                int r = r0 + i;
                u32 two = (u32)((w[i] >> 16) & 0xffffu) | ((u32)(w[i] >> 48) << 16);
                int off = r * 1024 + ((sc_c ^ (r & 7)) << 4) + sc_sub;
                *(u32*)((char*)hl + off) = two;
            }
        } else {
            #pragma unroll
            for (int i = 0; i < 16; ++i) {
                int r = r0 + i;
                int off = r * 1024 + ((sc_c ^ (r & 7)) << 4) + sc_sub;
                *(u32*)((char*)hl + off) = 0u;
            }
        }
        __syncthreads();   // (1) hl staged

        // ---- C: MFMA, wave (g,m): gate g, batch rows m*16..+15, K=512 ----
        {
            f32x4 acc = {0.f, 0.f, 0.f, 0.f};
            const int b0 = lane & 15, q = lane >> 4;
            #pragma unroll
            for (int kt = 0; kt < 16; ++kt) {
                int pc = ((kt << 2) + q) ^ (b0 & 7);
                bf16x8 a0 = *(const bf16x8*)&hl[(b0 + m * 16) * 512 + pc * 8];
                bf16x8 Bv = *(const bf16x8*)&Wfr[((g * 16 + kt) * 64 + lane) * 8];
                acc = __builtin_amdgcn_mfma_f32_16x16x32_bf16(a0, Bv, acc, 0, 0, 0);
            }
            // plane [g][batch][jj] stride 18: row = m*16 + q*4 + r, col = b0
            #pragma unroll
            for (int r = 0; r < 4; ++r)
                gates[g * 576 + (m * 16 + q * 4 + r) * 18 + b0] = acc[r];
        }
        __syncthreads();   // (2) gates ready

        // ---- D: epilogue, ONE column per thread (all 8 waves) ----
        {
            const float* xrow = &xq[s & 1][eb * 65];
            float gi = xrow[     ej] + gates[0 * 576 + eb * 18 + ej];
            float gf = xrow[16 + ej] + gates[1 * 576 + eb * 18 + ej];
            float gg = xrow[32 + ej] + gates[2 * 576 + eb * 18 + ej];
            float go = xrow[48 + ej] + gates[3 * 576 + eb * 18 + ej];
            float ig = 1.f / (1.f + __expf(-gi));
            float fg = 1.f / (1.f + __expf(-gf));
            float gt = tanhf(gg);
            float og = 1.f / (1.f + __expf(-go));
            float c  = fg * creg + ig * gt;
            float h  = og * tanhf(c);
            creg = c;

            // publish stamped h word FIRST (critical path), parity ping-pong
            u32* Hwr32 = (u32*)(Hd + ((size_t)(((s + 1) & 1) * 2 + dir)) * (32 * 256));
            const u32 pst = (u32)((layer << 10) | (s + 1));
            __hip_atomic_store(Hwr32 + eb * 512 + j0 + ej,
                               ((u32)f2b(h) << 16) | pst,
                               __ATOMIC_RELAXED, __HIP_MEMORY_SCOPE_AGENT);

            // software-pipelined poll: issue next step's loads NOW
            if (s + 1 < SS) {
                const u64* Hn = Hd + ((size_t)(((s + 1) & 1) * 2 + dir)) * (32 * 256);
                #pragma unroll
                for (int i = 0; i < 16; ++i)
                    w[i] = __hip_atomic_load(Hn + (r0 + i) * 256 + wd,
                                             __ATOMIC_RELAXED, __HIP_MEMORY_SCOPE_AGENT);
            }

            // slow-path outputs (off critical path)
            if (layer == 0) {
                hs0[(size_t)sa * (BB * 1024) + (size_t)eb * 1024 + dir * 512 + j0 + ej]
                    = f2b(h);
            } else {
                out[(size_t)eb * (SS * 1024) + (size_t)sa * 1024 + dir * 512 + j0 + ej] = h;
            }
            if (s == SS - 1) {
                int sl = layer * 2 + dir;
                fin[(size_t)sl * (32 * 512) + eb * 512 + j0 + ej] = h;
                fin[65536 + (size_t)sl * (32 * 512) + eb * 512 + j0 + ej] = c;
            }
        }
        // NO third barrier: xq double-buffered; hl rewrite gated by own poll
        // success (implies all WGs published => own epilogue reads retired);
        // uniform 2-barrier count per iteration => no barrier phase slip.
    }
}

// ---------------- workspace layout (bytes) ----------------
#define OFF_XBF   ((size_t)0)                       // 16,777,216
#define OFF_HS0   ((size_t)16777216)                // 33,554,432
#define OFF_XPF   ((size_t)50331648)                // 67,108,864
#define OFF_XPB   ((size_t)117440512)               // 67,108,864
#define OFF_WIH0F ((size_t)184549376)               // 2,097,152
#define OFF_WIH0B ((size_t)186646528)               // 2,097,152
#define OFF_WIH1F ((size_t)188743680)               // 4,194,304
#define OFF_WIH1B ((size_t)192937984)               // 4,194,304
#define OFF_HST   ((size_t)197132288)               // 262,144 (stamped h)

extern "C" void kernel_launch(void* const* d_in, const int* in_sizes, int n_in,
                              void* d_out, int out_size, void* d_ws, size_t ws_size,
                              hipStream_t stream) {
    const float* x      = (const float*)d_in[0];
    const float* wih0f  = (const float*)d_in[1];
    const float* whh0f  = (const float*)d_in[2];
    const float* bih0f  = (const float*)d_in[3];
    const float* bhh0f  = (const float*)d_in[4];
    const float* wih0b  = (const float*)d_in[5];
    const float* whh0b  = (const float*)d_in[6];
    const float* bih0b  = (const float*)d_in[7];
    const float* bhh0b  = (const float*)d_in[8];
    const float* wih1f  = (const float*)d_in[9];
    const float* whh1f  = (const float*)d_in[10];
    const float* bih1f  = (const float*)d_in[11];
    const float* bhh1f  = (const float*)d_in[12];
    const float* wih1b  = (const float*)d_in[13];
    const float* whh1b  = (const float*)d_in[14];
    const float* bih1b  = (const float*)d_in[15];
    const float* bhh1b  = (const float*)d_in[16];

    float* out = (float*)d_out;
    char* ws = (char*)d_ws;

    u16* xbf    = (u16*)(ws + OFF_XBF);
    u16* hs0    = (u16*)(ws + OFF_HS0);
    u16* xpf    = (u16*)(ws + OFF_XPF);
    u16* xpb    = (u16*)(ws + OFF_XPB);
    u16* bwih0f = (u16*)(ws + OFF_WIH0F);
    u16* bwih0b = (u16*)(ws + OFF_WIH0B);
    u16* bwih1f = (u16*)(ws + OFF_WIH1F);
    u16* bwih1b = (u16*)(ws + OFF_WIH1B);
    u64* Hd     = (u64*)(ws + OFF_HST);
    float* fin  = out + 16777216;   // final h stack, then c stack at +65536

    // converts
    k_convert_x<<<1024, 256, 0, stream>>>(x, xbf);
    k_cast<<<512, 256, 0, stream>>>(wih0f, bwih0f, 2048 * 512 / 4);
    k_cast<<<512, 256, 0, stream>>>(wih0b, bwih0b, 2048 * 512 / 4);
    k_cast<<<512, 256, 0, stream>>>(wih1f, bwih1f, 2048 * 1024 / 4);
    k_cast<<<512, 256, 0, stream>>>(wih1b, bwih1b, 2048 * 1024 / 4);

    // zero stamped-h buffer once (first-call garbage; stale stamps are
    // layer-tagged; leftover same-layer stamps from a previous replay carry
    // identical deterministic values, so a match is harmless)
    hipMemsetAsync(ws + OFF_HST, 0, 262144, stream);

    // layer 0
    k_proj<<<dim3(128, 16, 2), 256, 0, stream>>>(
        xbf, bwih0f, bwih0b, bih0f, bhh0f, bih0b, bhh0b, xpf, xpb, 512);
    k_rec<<<64, 512, 0, stream>>>(xpf, xpb, whh0f, whh0b, Hd,
                                  hs0, nullptr, fin, 0);

    // layer 1
    k_proj<<<dim3(128, 16, 2), 256, 0, stream>>>(
        hs0, bwih1f, bwih1b, bih1f, bhh1f, bih1b, bhh1b, xpf, xpb, 1024);
    k_rec<<<64, 512, 0, stream>>>(xpf, xpb, whh1f, whh1b, Hd,
                                  nullptr, out, fin, 1);
}